// Round 8
// baseline (346.582 us; speedup 1.0000x reference)
//
#include <hip/hip_runtime.h>
#include <math.h>

namespace {

constexpr int kB = 4;
constexpr int kN = 16384;
constexpr int kS = 4096;
constexpr int kD1 = 128;
constexpr int kD2 = 256;
constexpr int kCO = 256;
constexpr int kNCOL = kB * kN;   // 65536
constexpr int kKX = kD1 + kD2;   // 384, XT row stride

// ws layout (known-good bound 67375104 B):
//   pts4  @ 0         float4[16384]          262144 B
//   ab0   @ 262144    float[512]
//   X1pre @ 266240    bf16 [65536][256]      33554432 B  (layer-0 out; pre-BN until
//                                                         bnapply rewrites in-place)
//   partS @ 33820672  fp32 [256][512]        524288 B    } fea2t fp32 16MB overlays
//   partQ @ 34344960  fp32 [256][512]        524288 B    } [kOffPart,kOffWbf) til knn done
//   W0bf  @ 50597888  bf16 [256][384]        196608 B    (starts exactly at fea2t end)
//   W1bf  @ 50794496  bf16 [256][256]        131072 B    (end 50925568)
constexpr size_t kOffAb0  = 262144;
constexpr size_t kOffX1p  = 266240;
constexpr size_t kOffPart = 33820672;
constexpr size_t kOffWbf  = 50597888;   // = kOffPart + 16MB (fea2t size)
constexpr size_t kOffW1bf = 50794496;
// out buffer doubles as XT bf16 [65536][384] (50.3MB) until gemm1 writes out.

typedef __bf16 bf16x8 __attribute__((ext_vector_type(8)));
typedef float f32x4 __attribute__((ext_vector_type(4)));

__device__ __forceinline__ float bf2f(unsigned short u) {
  unsigned int x = ((unsigned int)u) << 16;
  float f;
  __builtin_memcpy(&f, &x, 4);
  return f;
}
__device__ __forceinline__ unsigned short f2bf(float f) {
  unsigned int x;
  __builtin_memcpy(&x, &f, 4);
  x += 0x7fffu + ((x >> 16) & 1u);  // RNE
  return (unsigned short)(x >> 16);
}

__device__ __forceinline__ void cp16_async(const void* g, void* l) {
#if __has_builtin(__builtin_amdgcn_global_load_lds)
  __builtin_amdgcn_global_load_lds(
      (const __attribute__((address_space(1))) unsigned int*)g,
      (__attribute__((address_space(3))) unsigned int*)l, 16, 0, 0);
#else
  *(uint4*)l = *(const uint4*)g;
#endif
}

// Fused front-end, 4 block segments:
//   [0,1024):    fea2 [b][c][s] -> fea2t [b][s][c] fp32 (64x64 LDS tiles)
//   [1024,1088): xyz2 -> pts4 {2x,2y,2z,|p|^2}
//   [1088,2112): fea1 [b][c][n] -> XT[j][0..127] bf16
//   [2112,2152): W0,W1 fp32 -> bf16 (RNE, bit-identical to in-GEMM cvt)
__global__ __launch_bounds__(256) void prep_kernel(
    const float* __restrict__ xyz2, float4* __restrict__ pts4,
    const float* __restrict__ fea2, float* __restrict__ fea2t,
    const float* __restrict__ fea1, unsigned short* __restrict__ XT,
    const float* __restrict__ W0, const float* __restrict__ W1,
    unsigned short* __restrict__ W0bf, unsigned short* __restrict__ W1bf) {
#pragma clang fp contract(off)
  __shared__ __align__(16) char lds_raw[33024];
  int bid = blockIdx.x;
  int t = threadIdx.x;
  if (bid >= 2112) {
    int gt = (bid - 2112) * 256 + t;
    int base = gt * 16;
    const float* src;
    unsigned short* dst;
    if (base < kCO * kKX) {
      src = W0 + base;
      dst = W0bf + base;
    } else {
      src = W1 + (base - kCO * kKX);
      dst = W1bf + (base - kCO * kKX);
    }
    float4 f0 = *(const float4*)(src);
    float4 f1 = *(const float4*)(src + 4);
    float4 f2 = *(const float4*)(src + 8);
    float4 f3 = *(const float4*)(src + 12);
    unsigned short h[16] = {f2bf(f0.x), f2bf(f0.y), f2bf(f0.z), f2bf(f0.w),
                            f2bf(f1.x), f2bf(f1.y), f2bf(f1.z), f2bf(f1.w),
                            f2bf(f2.x), f2bf(f2.y), f2bf(f2.z), f2bf(f2.w),
                            f2bf(f3.x), f2bf(f3.y), f2bf(f3.z), f2bf(f3.w)};
    ((uint4*)dst)[0] = ((uint4*)h)[0];
    ((uint4*)dst)[1] = ((uint4*)h)[1];
    return;
  }
  if (bid >= 1024 && bid < 1088) {
    int i = (bid - 1024) * 256 + t;
    float x = xyz2[i * 3 + 0];
    float y = xyz2[i * 3 + 1];
    float z = xyz2[i * 3 + 2];
    float4 p;
    p.w = (x * x + y * y) + z * z;
    p.x = x + x; p.y = y + y; p.z = z + z;
    pts4[i] = p;
    return;
  }
  if (bid < 1024) {
    float (*T)[65] = (float (*)[65])lds_raw;
    int s0 = (bid & 63) * 64;
    int c0 = ((bid >> 6) & 3) * 64;
    int b = bid >> 8;
    {
      int sl = t & 63, cg2 = t >> 6;
#pragma unroll
      for (int i = 0; i < 16; ++i) {
        int cl = cg2 * 16 + i;
        T[sl][cl] = fea2[((size_t)(b * kD2 + c0 + cl)) * kS + s0 + sl];
      }
    }
    __syncthreads();
    {
      int cl = t & 63, sg = t >> 6;
#pragma unroll
      for (int i = 0; i < 16; ++i) {
        int sl = sg * 16 + i;
        fea2t[((size_t)(b * kS + s0 + sl)) * kD2 + c0 + cl] = T[sl][cl];
      }
    }
    return;
  }
  // fea1 transpose segment
  {
    float (*T)[129] = (float (*)[129])lds_raw;
    int fb = bid - 1088;
    int n0 = (fb & 255) * 64;
    int b = fb >> 8;
    {
      int nl = t & 63, cg2 = t >> 6;  // cg2 0..3
#pragma unroll
      for (int i = 0; i < 32; ++i) {
        int c = cg2 * 32 + i;
        T[nl][c] = fea1[((size_t)(b * kD1 + c)) * kN + n0 + nl];
      }
    }
    __syncthreads();
    {
      int nl = t >> 2, ch = t & 3;  // 32 channels per thread
      unsigned short h[32];
#pragma unroll
      for (int i = 0; i < 32; ++i) h[i] = f2bf(T[nl][ch * 32 + i]);
      uint4* dst = (uint4*)&XT[(size_t)(b * kN + n0 + nl) * kKX + ch * 32];
#pragma unroll
      for (int i = 0; i < 4; ++i) dst[i] = ((uint4*)h)[i];
    }
  }
}

// Block = 512 threads = 64 queries x 8 chunks of 512 points (round-3 form:
// 13.8KB LDS, occupancy 66%, VALU-bound 87% -- do NOT grow this kernel's
// LDS/barrier footprint; r4's fused transpose cost +20us).
__global__ __launch_bounds__(512) void knn_interp_kernel(
    const float* __restrict__ xyz1, const float4* __restrict__ pts4,
    const float* __restrict__ fea2t, unsigned short* __restrict__ XT) {
#pragma clang fp contract(off)
  __shared__ float cd[8][64][3];
  __shared__ int ci[8][64][3];
  __shared__ float wsh[3][64];
  __shared__ int ish[3][64];
  int tid = threadIdx.x;
  int q = tid & 63;
  int chunk = __builtin_amdgcn_readfirstlane(tid >> 6);  // 0..7, wave-uniform
  int b = blockIdx.x >> 8;                 // scalar (256 blocks per batch)
  int n0 = (blockIdx.x & 255) * 64;        // scalar
  int n = n0 + q;
  int qg = b * kN + n;

  const float* p1 = xyz1 + (size_t)qg * 3;
  float x = p1[0], y = p1[1], z = p1[2];
  float n1 = (x * x + y * y) + z * z;

  const float4* pp = pts4 + b * kS + chunk * 512;  // scalar base
  int sbase = chunk * 512;
  float d0v = 1e30f, d1v = 1e30f, d2v = 1e30f;
  int i0 = 0, i1 = 0, i2 = 0;
  for (int s = 0; s < 512; s += 4) {
    float4 P[4];
    P[0] = pp[s]; P[1] = pp[s + 1]; P[2] = pp[s + 2]; P[3] = pp[s + 3];
#pragma unroll
    for (int u = 0; u < 4; ++u) {
      float dot2 = (x * P[u].x + y * P[u].y) + z * P[u].z;
      float d = (n1 + P[u].w) - dot2;
      if (__ballot(d < d2v)) {  // wave-uniform skip of the insert
        int si = sbase + s + u;
        bool b0 = d < d0v, b1 = d < d1v, b2 = d < d2v;
        int i2n = b1 ? i1 : (b2 ? si : i2);
        int i1n = b0 ? i0 : (b1 ? si : i1);
        int i0n = b0 ? si : i0;
        d2v = __builtin_amdgcn_fmed3f(d1v, d, d2v);
        d1v = __builtin_amdgcn_fmed3f(d0v, d, d1v);
        d0v = fminf(d0v, d);
        i0 = i0n; i1 = i1n; i2 = i2n;
      }
    }
  }
  cd[chunk][q][0] = d0v; cd[chunk][q][1] = d1v; cd[chunk][q][2] = d2v;
  ci[chunk][q][0] = i0;  ci[chunk][q][1] = i1;  ci[chunk][q][2] = i2;
  __syncthreads();

  if (tid < 64) {
    float D0 = 1e30f, D1 = 1e30f, D2 = 1e30f;
    int I0 = -1, I1 = -1, I2 = -1;
    for (int c2 = 0; c2 < 8; ++c2) {
#pragma unroll
      for (int k = 0; k < 3; ++k) {
        float d = cd[c2][tid][k];
        int i = ci[c2][tid][k];
        bool q0 = (d < D0) || (d == D0 && i < I0);
        bool q1 = (d < D1) || (d == D1 && i < I1);
        bool q2 = (d < D2) || (d == D2 && i < I2);
        if (q0)      { D2 = D1; I2 = I1; D1 = D0; I1 = I0; D0 = d; I0 = i; }
        else if (q1) { D2 = D1; I2 = I1; D1 = d;  I1 = i; }
        else if (q2) { D2 = d;  I2 = i; }
      }
    }
    float r0 = 1.0f / fmaxf(D0, 1e-8f);
    float r1 = 1.0f / fmaxf(D1, 1e-8f);
    float r2 = 1.0f / fmaxf(D2, 1e-8f);
    float rs = (r0 + r1) + r2;
    wsh[0][tid] = r0 / rs; wsh[1][tid] = r1 / rs; wsh[2][tid] = r2 / rs;
    ish[0][tid] = I0; ish[1][tid] = I1; ish[2][tid] = I2;
  }
  __syncthreads();

  // Interp/gather: 8 lanes per query, coalesced reads + 64B-line writes.
  int gq = tid >> 3, l = tid & 7;
  float w0 = wsh[0][gq], w1 = wsh[1][gq], w2 = wsh[2][gq];
  int qg2 = b * kN + n0 + gq;
  const float* fb = fea2t + ((size_t)b * kS) * kD2;
  const float* g0p = fb + (size_t)ish[0][gq] * kD2;
  const float* g1p = fb + (size_t)ish[1][gq] * kD2;
  const float* g2p = fb + (size_t)ish[2][gq] * kD2;
  unsigned short* op = XT + (size_t)qg2 * kKX + kD1;  // cols 128..383
#pragma unroll
  for (int k = 0; k < 8; ++k) {
    int c = (l + 8 * k) * 4;
    float4 f0 = *(const float4*)(g0p + c);
    float4 f1 = *(const float4*)(g1p + c);
    float4 f2 = *(const float4*)(g2p + c);
    unsigned short h[4];
    h[0] = f2bf((w0 * f0.x + w1 * f1.x) + w2 * f2.x);
    h[1] = f2bf((w0 * f0.y + w1 * f1.y) + w2 * f2.y);
    h[2] = f2bf((w0 * f0.z + w1 * f1.z) + w2 * f2.z);
    h[3] = f2bf((w0 * f0.w + w1 * f1.w) + w2 * f2.w);
    *(uint2*)(op + c) = *(uint2*)h;
  }
}

// Layer-0 GEMM. A = pre-converted W0bf (uint4 loads; padded ALD=40 layout
// kept for 2-way-conflict-free A reads). Writes X1pre[j][o] bf16 (pre-BN,
// LDS-transposed) + transposed per-block BN partials (no atomics).
__global__ __launch_bounds__(256) void gemm0t_kernel(
    const unsigned short* __restrict__ Wbf, const unsigned short* __restrict__ Bt,
    const float* __restrict__ bias, unsigned short* __restrict__ X1pre,
    float* __restrict__ partS, float* __restrict__ partQ) {
  constexpr int KDIM = kKX;
  constexpr int ALD = 40;
  __shared__ unsigned short smem[9216];   // As[128*40] + Bs[128*32]; reused as T
  unsigned short* As = smem;
  unsigned short* Bs = smem + 128 * ALD;
  __shared__ float psum[2][128], pq[2][128];
  int tid = threadIdx.x;
  int j0 = blockIdx.x * 128;
  int m0 = blockIdx.y * 128;
  int w = tid >> 6, lane = tid & 63;
  int wm = w & 1, wn = w >> 1;
  int quad = lane >> 4, l16 = lane & 15;
  int arow = tid & 127, ahalf = tid >> 7;
  int brow = tid >> 2, bch = tid & 3;

  // runtime C/D layout probe
  bf16x8 pone, pm;
#pragma unroll
  for (int i = 0; i < 8; ++i) { pone[i] = (__bf16)1.0f; pm[i] = (__bf16)(float)l16; }
  f32x4 zf = {};
  f32x4 dr = __builtin_amdgcn_mfma_f32_16x16x32_bf16(pm, pone, zf, 0, 0, 0);
  f32x4 dc = __builtin_amdgcn_mfma_f32_16x16x32_bf16(pone, pm, zf, 0, 0, 0);
  int rowv[4], colv[4];
#pragma unroll
  for (int r = 0; r < 4; ++r) {
    rowv[r] = (int)(dr[r] * (1.0f / 32.0f) + 0.5f);
    colv[r] = (int)(dc[r] * (1.0f / 32.0f) + 0.5f);
  }

  f32x4 acc[4][4] = {};
  for (int k0 = 0; k0 < KDIM; k0 += 32) {
    cp16_async(Bt + (size_t)(j0 + brow) * KDIM + k0 + bch * 8, &Bs[(size_t)tid * 8]);
    cp16_async(Bt + (size_t)(j0 + 64 + brow) * KDIM + k0 + bch * 8, &Bs[(size_t)(tid + 256) * 8]);
    {
      const unsigned short* ap = Wbf + (size_t)(m0 + arow) * KDIM + k0 + ahalf * 16;
      uint4 u0 = ((const uint4*)ap)[0];
      uint4 u1 = ((const uint4*)ap)[1];
      uint4* dst = (uint4*)&As[arow * ALD + ahalf * 16];
      dst[0] = u0;
      dst[1] = u1;
    }
    __syncthreads();
    bf16x8 af[4], bfr[4];
#pragma unroll
    for (int mt = 0; mt < 4; ++mt)
      af[mt] = *(const bf16x8*)(&As[(wm * 64 + mt * 16 + l16) * ALD + quad * 8]);
#pragma unroll
    for (int nt = 0; nt < 4; ++nt)
      bfr[nt] = *(const bf16x8*)(&Bs[(wn * 64 + nt * 16 + l16) * 32 + quad * 8]);
#pragma unroll
    for (int mt = 0; mt < 4; ++mt)
#pragma unroll
      for (int nt = 0; nt < 4; ++nt)
        acc[mt][nt] = __builtin_amdgcn_mfma_f32_16x16x32_bf16(af[mt], bfr[nt], acc[mt][nt], 0, 0, 0);
    __syncthreads();
  }

  // Epilogue: v = acc + bias; pack bf16 quads; per-(mt,r) stats reduce.
  uint2 h2[4][4];
#pragma unroll
  for (int mt = 0; mt < 4; ++mt) {
    int obase = m0 + wm * 64 + mt * 16 + rowv[0];
    float4 bv4 = *(const float4*)&bias[obase];
    float s4[4] = {0.f, 0.f, 0.f, 0.f}, q4[4] = {0.f, 0.f, 0.f, 0.f};
#pragma unroll
    for (int nt = 0; nt < 4; ++nt) {
      unsigned short hh[4];
#pragma unroll
      for (int r = 0; r < 4; ++r) {
        float v = acc[mt][nt][r] + ((const float*)&bv4)[r];
        s4[r] += v; q4[r] += v * v;
        hh[r] = f2bf(v);
      }
      h2[mt][nt] = *(uint2*)hh;
    }
#pragma unroll
    for (int r = 0; r < 4; ++r) {
      float s = s4[r], qq = q4[r];
#pragma unroll
      for (int d2 = 1; d2 < 16; d2 <<= 1) {
        s += __shfl_xor(s, d2, 64);
        qq += __shfl_xor(qq, d2, 64);
      }
      if (l16 == 0) {
        int ol = wm * 64 + mt * 16 + rowv[0] + r;
        psum[wn][ol] = s;
        pq[wn][ol] = qq;
      }
    }
  }

  // Transposed store in two wave-rounds through the dead As/Bs LDS.
  unsigned short* T = smem + wm * 4608;  // 64*72
  int jr = lane >> 3, cc = lane & 7;
  if (wn == 0) {
#pragma unroll
    for (int mt = 0; mt < 4; ++mt)
#pragma unroll
      for (int nt = 0; nt < 4; ++nt)
        *(uint2*)&T[(nt * 16 + colv[0]) * 72 + mt * 16 + rowv[0]] = h2[mt][nt];
#pragma unroll
    for (int it = 0; it < 8; ++it) {
      int jl = it * 8 + jr;
      uint4 u = *(uint4*)&T[jl * 72 + cc * 8];
      *(uint4*)&X1pre[(size_t)(j0 + jl) * kCO + m0 + wm * 64 + cc * 8] = u;
    }
  }
  __syncthreads();
  if (wn == 1) {
#pragma unroll
    for (int mt = 0; mt < 4; ++mt)
#pragma unroll
      for (int nt = 0; nt < 4; ++nt)
        *(uint2*)&T[(nt * 16 + colv[0]) * 72 + mt * 16 + rowv[0]] = h2[mt][nt];
#pragma unroll
    for (int it = 0; it < 8; ++it) {
      int jl = it * 8 + jr;
      uint4 u = *(uint4*)&T[jl * 72 + cc * 8];
      *(uint4*)&X1pre[(size_t)(j0 + 64 + jl) * kCO + m0 + wm * 64 + cc * 8] = u;
    }
  }
  if (tid < 128) {
    float ss = psum[0][tid] + psum[1][tid];
    float qq = pq[0][tid] + pq[1][tid];
    partS[(size_t)(m0 + tid) * 512 + blockIdx.x] = ss;
    partQ[(size_t)(m0 + tid) * 512 + blockIdx.x] = qq;
  }
}

// Reduce per-block partials (part[o][512], contiguous) -> BN affine coefs.
__global__ __launch_bounds__(64) void redstats_kernel(
    const float* __restrict__ pS, const float* __restrict__ pQ,
    const float* __restrict__ gamma, const float* __restrict__ beta,
    float* __restrict__ ab) {
  int o = blockIdx.x, t = threadIdx.x;
  float s = 0.f, q = 0.f;
  for (int i = t; i < 512; i += 64) {
    s += pS[(size_t)o * 512 + i];
    q += pQ[(size_t)o * 512 + i];
  }
#pragma unroll
  for (int d = 1; d < 64; d <<= 1) {
    s += __shfl_xor(s, d, 64);
    q += __shfl_xor(q, d, 64);
  }
  if (t == 0) {
    float m = s * (1.0f / 65536.f);
    float var = q * (1.0f / 65536.f) - m * m;
    float rsq = 1.0f / sqrtf(var + 1e-5f);
    float a = gamma[o] * rsq;
    ab[o] = a;
    ab[kCO + o] = beta[o] - m * a;
  }
}

// In-place BN affine + ReLU on X1pre [j][256] bf16 (hoisted out of gemm1f's
// B-staging; same math order -> bit-identical to the previous inline form).
// Memory-bound: 67MB R+W. Coefs from L2-hot ab0 via aligned float4 loads.
__global__ __launch_bounds__(256) void bnapply_kernel(
    unsigned short* __restrict__ X, const float* __restrict__ ab0) {
  size_t idx = ((size_t)blockIdx.x * 256 + threadIdx.x) * 8;
  int o0 = (int)(idx & 255);  // multiple of 8 -> 16B-aligned coef loads
  float4 a0 = *(const float4*)&ab0[o0];
  float4 a1 = *(const float4*)&ab0[o0 + 4];
  float4 c0 = *(const float4*)&ab0[kCO + o0];
  float4 c1 = *(const float4*)&ab0[kCO + o0 + 4];
  uint4 raw = *(uint4*)(X + idx);
  const unsigned short* rs = (const unsigned short*)&raw;
  unsigned short o8[8];
  o8[0] = f2bf(fmaxf(fmaf(a0.x, bf2f(rs[0]), c0.x), 0.f));
  o8[1] = f2bf(fmaxf(fmaf(a0.y, bf2f(rs[1]), c0.y), 0.f));
  o8[2] = f2bf(fmaxf(fmaf(a0.z, bf2f(rs[2]), c0.z), 0.f));
  o8[3] = f2bf(fmaxf(fmaf(a0.w, bf2f(rs[3]), c0.w), 0.f));
  o8[4] = f2bf(fmaxf(fmaf(a1.x, bf2f(rs[4]), c1.x), 0.f));
  o8[5] = f2bf(fmaxf(fmaf(a1.y, bf2f(rs[5]), c1.y), 0.f));
  o8[6] = f2bf(fmaxf(fmaf(a1.z, bf2f(rs[6]), c1.z), 0.f));
  o8[7] = f2bf(fmaxf(fmaf(a1.w, bf2f(rs[7]), c1.w), 0.f));
  *(uint4*)(X + idx) = *(uint4*)o8;
}

// Layer-1 GEMM. A = pre-converted W1bf; B = post-BN X1 staged via pure
// cp16_async (BN hoisted to bnapply -> structurally identical to gemm0t).
// Epilogue writes fp32 out [b][o][n] + transposed per-block partials.
__global__ __launch_bounds__(256) void gemm1f_kernel(
    const unsigned short* __restrict__ Wbf, const unsigned short* __restrict__ Xp,
    const float* __restrict__ bias, float* __restrict__ out,
    float* __restrict__ partS, float* __restrict__ partQ) {
  constexpr int KDIM = kCO;
  constexpr int ALD = 40;
  __shared__ unsigned short As[128 * ALD];
  __shared__ unsigned short Bs[128 * 32];
  __shared__ float psum[2][128], pq[2][128];
  int tid = threadIdx.x;
  int j0 = blockIdx.x * 128;
  int m0 = blockIdx.y * 128;
  int w = tid >> 6, lane = tid & 63;
  int wm = w & 1, wn = w >> 1;
  int quad = lane >> 4, l16 = lane & 15;
  int arow = tid & 127, ahalf = tid >> 7;
  int brow = tid >> 2, bch = tid & 3;

  bf16x8 pone, pm;
#pragma unroll
  for (int i = 0; i < 8; ++i) { pone[i] = (__bf16)1.0f; pm[i] = (__bf16)(float)l16; }
  f32x4 zf = {};
  f32x4 dr = __builtin_amdgcn_mfma_f32_16x16x32_bf16(pm, pone, zf, 0, 0, 0);
  f32x4 dc = __builtin_amdgcn_mfma_f32_16x16x32_bf16(pone, pm, zf, 0, 0, 0);
  int rowv[4], colv[4];
#pragma unroll
  for (int r = 0; r < 4; ++r) {
    rowv[r] = (int)(dr[r] * (1.0f / 32.0f) + 0.5f);
    colv[r] = (int)(dc[r] * (1.0f / 32.0f) + 0.5f);
  }

  f32x4 acc[4][4] = {};
  for (int k0 = 0; k0 < KDIM; k0 += 32) {
    cp16_async(Xp + (size_t)(j0 + brow) * KDIM + k0 + bch * 8, &Bs[(size_t)tid * 8]);
    cp16_async(Xp + (size_t)(j0 + 64 + brow) * KDIM + k0 + bch * 8, &Bs[(size_t)(tid + 256) * 8]);
    {
      const unsigned short* ap = Wbf + (size_t)(m0 + arow) * KDIM + k0 + ahalf * 16;
      uint4 u0 = ((const uint4*)ap)[0];
      uint4 u1 = ((const uint4*)ap)[1];
      uint4* dst = (uint4*)&As[arow * ALD + ahalf * 16];
      dst[0] = u0;
      dst[1] = u1;
    }
    __syncthreads();
    bf16x8 af[4], bfr[4];
#pragma unroll
    for (int mt = 0; mt < 4; ++mt)
      af[mt] = *(const bf16x8*)(&As[(wm * 64 + mt * 16 + l16) * ALD + quad * 8]);
#pragma unroll
    for (int nt = 0; nt < 4; ++nt)
      bfr[nt] = *(const bf16x8*)(&Bs[(wn * 64 + nt * 16 + l16) * 32 + quad * 8]);
#pragma unroll
    for (int mt = 0; mt < 4; ++mt)
#pragma unroll
      for (int nt = 0; nt < 4; ++nt)
        acc[mt][nt] = __builtin_amdgcn_mfma_f32_16x16x32_bf16(af[mt], bfr[nt], acc[mt][nt], 0, 0, 0);
    __syncthreads();
  }

#pragma unroll
  for (int mt = 0; mt < 4; ++mt) {
#pragma unroll
    for (int r = 0; r < 4; ++r) {
      int ol = wm * 64 + mt * 16 + rowv[r];
      int o = m0 + ol;
      float bv = bias[o];
      float s = 0.f, qq = 0.f;
#pragma unroll
      for (int nt = 0; nt < 4; ++nt) {
        int j = j0 + wn * 64 + nt * 16 + colv[r];
        float v = acc[mt][nt][r] + bv;
        s += v; qq += v * v;
        int bb = j >> 14, nn = j & (kN - 1);
        out[((size_t)(bb * kCO + o)) * kN + nn] = v;
      }
#pragma unroll
      for (int d2 = 1; d2 < 16; d2 <<= 1) {
        s += __shfl_xor(s, d2, 64);
        qq += __shfl_xor(qq, d2, 64);
      }
      if (l16 == 0) {
        psum[wn][ol] = s;
        pq[wn][ol] = qq;
      }
    }
  }
  __syncthreads();
  if (tid < 128) {
    float ss = psum[0][tid] + psum[1][tid];
    float qq = pq[0][tid] + pq[1][tid];
    partS[(size_t)(m0 + tid) * 512 + blockIdx.x] = ss;
    partQ[(size_t)(m0 + tid) * 512 + blockIdx.x] = qq;
  }
}

// Final BN+ReLU with inlined stats reduction: each block spans 1024 elements
// of a single channel o; reduces part[o][0..512) (contiguous, L2-hot) and
// applies the affine in one pass.
__global__ __launch_bounds__(256) void finalf_kernel(
    float* __restrict__ Y, const float* __restrict__ pS,
    const float* __restrict__ pQ, const float* __restrict__ gamma,
    const float* __restrict__ beta) {
  __shared__ float sw[4], qw[4], coef[2];
  size_t base = (size_t)blockIdx.x * 1024;
  int o = (int)((base >> 14) & (kCO - 1));
  int tid = threadIdx.x;
  float s = pS[(size_t)o * 512 + tid] + pS[(size_t)o * 512 + 256 + tid];
  float q = pQ[(size_t)o * 512 + tid] + pQ[(size_t)o * 512 + 256 + tid];
#pragma unroll
  for (int d = 1; d < 64; d <<= 1) {
    s += __shfl_xor(s, d, 64);
    q += __shfl_xor(q, d, 64);
  }
  if ((tid & 63) == 0) { sw[tid >> 6] = s; qw[tid >> 6] = q; }
  __syncthreads();
  if (tid == 0) {
    float st = (sw[0] + sw[1]) + (sw[2] + sw[3]);
    float qt = (qw[0] + qw[1]) + (qw[2] + qw[3]);
    float m = st * (1.0f / 65536.f);
    float var = qt * (1.0f / 65536.f) - m * m;
    float rsq = 1.0f / sqrtf(var + 1e-5f);
    float a = gamma[o] * rsq;
    coef[0] = a;
    coef[1] = beta[o] - m * a;
  }
  __syncthreads();
  float a = coef[0], c = coef[1];
  float4 u = *(float4*)(Y + base + tid * 4);
  float* t = (float*)&u;
#pragma unroll
  for (int k = 0; k < 4; ++k) t[k] = fmaxf(fmaf(a, t[k], c), 0.0f);
  *(float4*)(Y + base + tid * 4) = u;
}

}  // namespace

extern "C" void kernel_launch(void* const* d_in, const int* in_sizes, int n_in,
                              void* d_out, int out_size, void* d_ws, size_t ws_size,
                              hipStream_t stream) {
  const float* xyz1 = (const float*)d_in[0];
  const float* xyz2 = (const float*)d_in[1];
  const float* fea1 = (const float*)d_in[2];
  const float* fea2 = (const float*)d_in[3];
  const float* W0 = (const float*)d_in[4];
  const float* b0 = (const float*)d_in[5];
  const float* g0 = (const float*)d_in[6];
  const float* be0 = (const float*)d_in[7];
  const float* W1 = (const float*)d_in[8];
  const float* b1 = (const float*)d_in[9];
  const float* g1 = (const float*)d_in[10];
  const float* be1 = (const float*)d_in[11];
  float* out = (float*)d_out;

  char* ws = (char*)d_ws;
  float4* pts4 = (float4*)ws;
  float* ab0 = (float*)(ws + kOffAb0);
  unsigned short* X1pre = (unsigned short*)(ws + kOffX1p);
  float* partS = (float*)(ws + kOffPart);
  float* partQ = (float*)(ws + kOffPart + 524288);
  float* fea2t = (float*)(ws + kOffPart);          // overlays partials, dead after knn
  unsigned short* W0bf = (unsigned short*)(ws + kOffWbf);
  unsigned short* W1bf = (unsigned short*)(ws + kOffW1bf);
  unsigned short* XT = (unsigned short*)d_out;     // bf16 [65536][384], dead after gemm0

  if (ws_size < kOffW1bf + (size_t)kCO * kCO * 2) return;

  prep_kernel<<<2152, 256, 0, stream>>>(xyz2, pts4, fea2, fea2t, fea1, XT,
                                        W0, W1, W0bf, W1bf);
  knn_interp_kernel<<<kNCOL / 64, 512, 0, stream>>>(xyz1, pts4, fea2t, XT);
  gemm0t_kernel<<<dim3(kNCOL / 128, kCO / 128), 256, 0, stream>>>(W0bf, XT, b0, X1pre, partS, partQ);
  redstats_kernel<<<kCO, 64, 0, stream>>>(partS, partQ, g0, be0, ab0);
  bnapply_kernel<<<kNCOL * kCO / (256 * 8), 256, 0, stream>>>(X1pre, ab0);
  gemm1f_kernel<<<dim3(kNCOL / 128, kCO / 128), 256, 0, stream>>>(W1bf, X1pre, b1, out, partS, partQ);
  finalf_kernel<<<kCO * kNCOL / (256 * 4), 256, 0, stream>>>(out, partS, partQ, g1, be1);
}

// Round 9
// 337.682 us; speedup vs baseline: 1.0264x; 1.0264x over previous
//
#include <hip/hip_runtime.h>
#include <math.h>

namespace {

constexpr int kB = 4;
constexpr int kN = 16384;
constexpr int kS = 4096;
constexpr int kD1 = 128;
constexpr int kD2 = 256;
constexpr int kCO = 256;
constexpr int kNCOL = kB * kN;   // 65536
constexpr int kKX = kD1 + kD2;   // 384, XT row stride

// ws layout (known-good bound 67375104 B):
//   pts4  @ 0         float4[16384]          262144 B
//   ab0   @ 262144    float[512]
//   X1pre @ 266240    bf16 [65536][256]      33554432 B  (pre-BN layer-0 out, j-major)
//   partS @ 33820672  fp32 [256][512]        524288 B    } fea2t fp32 16MB overlays
//   partQ @ 34344960  fp32 [256][512]        524288 B    } [kOffPart,kOffWbf) til knn done
//   W0bf  @ 50597888  bf16 [256][384]        196608 B    (starts exactly at fea2t end)
//   W1bf  @ 50794496  bf16 [256][256]        131072 B    (end 50925568)
constexpr size_t kOffAb0  = 262144;
constexpr size_t kOffX1p  = 266240;
constexpr size_t kOffPart = 33820672;
constexpr size_t kOffWbf  = 50597888;   // = kOffPart + 16MB (fea2t size)
constexpr size_t kOffW1bf = 50794496;
// out buffer doubles as XT bf16 [65536][384] (50.3MB) until gemm1 writes out.

typedef __bf16 bf16x8 __attribute__((ext_vector_type(8)));
typedef float f32x4 __attribute__((ext_vector_type(4)));

__device__ __forceinline__ float bf2f(unsigned short u) {
  unsigned int x = ((unsigned int)u) << 16;
  float f;
  __builtin_memcpy(&f, &x, 4);
  return f;
}
__device__ __forceinline__ unsigned short f2bf(float f) {
  unsigned int x;
  __builtin_memcpy(&x, &f, 4);
  x += 0x7fffu + ((x >> 16) & 1u);  // RNE
  return (unsigned short)(x >> 16);
}

__device__ __forceinline__ void cp16_async(const void* g, void* l) {
#if __has_builtin(__builtin_amdgcn_global_load_lds)
  __builtin_amdgcn_global_load_lds(
      (const __attribute__((address_space(1))) unsigned int*)g,
      (__attribute__((address_space(3))) unsigned int*)l, 16, 0, 0);
#else
  *(uint4*)l = *(const uint4*)g;
#endif
}

// LDS chunk swizzle for [128][32]-ushort tiles staged via cp16_async:
// 16B chunk slot (row, q) holds global column (q ^ xr(row)),
// xr(row) = (row&3) ^ ((row>>2)&3). Readers fetch chunk quad^xr(row):
// 16 lanes -> 8 distinct 4-bank windows = 2-way (free, m136), vs the 8-way
// conflict of the linear layout. Source-side permutation only (G21): LDS
// dest stays wave-linear as cp16_async requires.

// Fused front-end, 4 block segments:
//   [0,1024):    fea2 [b][c][s] -> fea2t [b][s][c] fp32 (64x64 LDS tiles)
//   [1024,1088): xyz2 -> pts4 {2x,2y,2z,|p|^2}
//   [1088,2112): fea1 [b][c][n] -> XT[j][0..127] bf16
//   [2112,2152): W0,W1 fp32 -> bf16 (RNE, bit-identical to in-GEMM cvt)
__global__ __launch_bounds__(256) void prep_kernel(
    const float* __restrict__ xyz2, float4* __restrict__ pts4,
    const float* __restrict__ fea2, float* __restrict__ fea2t,
    const float* __restrict__ fea1, unsigned short* __restrict__ XT,
    const float* __restrict__ W0, const float* __restrict__ W1,
    unsigned short* __restrict__ W0bf, unsigned short* __restrict__ W1bf) {
#pragma clang fp contract(off)
  __shared__ __align__(16) char lds_raw[33024];
  int bid = blockIdx.x;
  int t = threadIdx.x;
  if (bid >= 2112) {
    int gt = (bid - 2112) * 256 + t;
    int base = gt * 16;
    const float* src;
    unsigned short* dst;
    if (base < kCO * kKX) {
      src = W0 + base;
      dst = W0bf + base;
    } else {
      src = W1 + (base - kCO * kKX);
      dst = W1bf + (base - kCO * kKX);
    }
    float4 f0 = *(const float4*)(src);
    float4 f1 = *(const float4*)(src + 4);
    float4 f2 = *(const float4*)(src + 8);
    float4 f3 = *(const float4*)(src + 12);
    unsigned short h[16] = {f2bf(f0.x), f2bf(f0.y), f2bf(f0.z), f2bf(f0.w),
                            f2bf(f1.x), f2bf(f1.y), f2bf(f1.z), f2bf(f1.w),
                            f2bf(f2.x), f2bf(f2.y), f2bf(f2.z), f2bf(f2.w),
                            f2bf(f3.x), f2bf(f3.y), f2bf(f3.z), f2bf(f3.w)};
    ((uint4*)dst)[0] = ((uint4*)h)[0];
    ((uint4*)dst)[1] = ((uint4*)h)[1];
    return;
  }
  if (bid >= 1024 && bid < 1088) {
    int i = (bid - 1024) * 256 + t;
    float x = xyz2[i * 3 + 0];
    float y = xyz2[i * 3 + 1];
    float z = xyz2[i * 3 + 2];
    float4 p;
    p.w = (x * x + y * y) + z * z;
    p.x = x + x; p.y = y + y; p.z = z + z;
    pts4[i] = p;
    return;
  }
  if (bid < 1024) {
    float (*T)[65] = (float (*)[65])lds_raw;
    int s0 = (bid & 63) * 64;
    int c0 = ((bid >> 6) & 3) * 64;
    int b = bid >> 8;
    {
      int sl = t & 63, cg2 = t >> 6;
#pragma unroll
      for (int i = 0; i < 16; ++i) {
        int cl = cg2 * 16 + i;
        T[sl][cl] = fea2[((size_t)(b * kD2 + c0 + cl)) * kS + s0 + sl];
      }
    }
    __syncthreads();
    {
      int cl = t & 63, sg = t >> 6;
#pragma unroll
      for (int i = 0; i < 16; ++i) {
        int sl = sg * 16 + i;
        fea2t[((size_t)(b * kS + s0 + sl)) * kD2 + c0 + cl] = T[sl][cl];
      }
    }
    return;
  }
  // fea1 transpose segment
  {
    float (*T)[129] = (float (*)[129])lds_raw;
    int fb = bid - 1088;
    int n0 = (fb & 255) * 64;
    int b = fb >> 8;
    {
      int nl = t & 63, cg2 = t >> 6;  // cg2 0..3
#pragma unroll
      for (int i = 0; i < 32; ++i) {
        int c = cg2 * 32 + i;
        T[nl][c] = fea1[((size_t)(b * kD1 + c)) * kN + n0 + nl];
      }
    }
    __syncthreads();
    {
      int nl = t >> 2, ch = t & 3;  // 32 channels per thread
      unsigned short h[32];
#pragma unroll
      for (int i = 0; i < 32; ++i) h[i] = f2bf(T[nl][ch * 32 + i]);
      uint4* dst = (uint4*)&XT[(size_t)(b * kN + n0 + nl) * kKX + ch * 32];
#pragma unroll
      for (int i = 0; i < 4; ++i) dst[i] = ((uint4*)h)[i];
    }
  }
}

// Block = 512 threads = 64 queries x 8 chunks of 512 points (round-3 form:
// 13.8KB LDS, occupancy 66%, VALU-bound 87% -- do NOT grow this kernel's
// LDS/barrier footprint; r4's fused transpose cost +20us).
__global__ __launch_bounds__(512) void knn_interp_kernel(
    const float* __restrict__ xyz1, const float4* __restrict__ pts4,
    const float* __restrict__ fea2t, unsigned short* __restrict__ XT) {
#pragma clang fp contract(off)
  __shared__ float cd[8][64][3];
  __shared__ int ci[8][64][3];
  __shared__ float wsh[3][64];
  __shared__ int ish[3][64];
  int tid = threadIdx.x;
  int q = tid & 63;
  int chunk = __builtin_amdgcn_readfirstlane(tid >> 6);  // 0..7, wave-uniform
  int b = blockIdx.x >> 8;                 // scalar (256 blocks per batch)
  int n0 = (blockIdx.x & 255) * 64;        // scalar
  int n = n0 + q;
  int qg = b * kN + n;

  const float* p1 = xyz1 + (size_t)qg * 3;
  float x = p1[0], y = p1[1], z = p1[2];
  float n1 = (x * x + y * y) + z * z;

  const float4* pp = pts4 + b * kS + chunk * 512;  // scalar base
  int sbase = chunk * 512;
  float d0v = 1e30f, d1v = 1e30f, d2v = 1e30f;
  int i0 = 0, i1 = 0, i2 = 0;
  for (int s = 0; s < 512; s += 4) {
    float4 P[4];
    P[0] = pp[s]; P[1] = pp[s + 1]; P[2] = pp[s + 2]; P[3] = pp[s + 3];
#pragma unroll
    for (int u = 0; u < 4; ++u) {
      float dot2 = (x * P[u].x + y * P[u].y) + z * P[u].z;
      float d = (n1 + P[u].w) - dot2;
      if (__ballot(d < d2v)) {  // wave-uniform skip of the insert
        int si = sbase + s + u;
        bool b0 = d < d0v, b1 = d < d1v, b2 = d < d2v;
        int i2n = b1 ? i1 : (b2 ? si : i2);
        int i1n = b0 ? i0 : (b1 ? si : i1);
        int i0n = b0 ? si : i0;
        d2v = __builtin_amdgcn_fmed3f(d1v, d, d2v);
        d1v = __builtin_amdgcn_fmed3f(d0v, d, d1v);
        d0v = fminf(d0v, d);
        i0 = i0n; i1 = i1n; i2 = i2n;
      }
    }
  }
  cd[chunk][q][0] = d0v; cd[chunk][q][1] = d1v; cd[chunk][q][2] = d2v;
  ci[chunk][q][0] = i0;  ci[chunk][q][1] = i1;  ci[chunk][q][2] = i2;
  __syncthreads();

  if (tid < 64) {
    float D0 = 1e30f, D1 = 1e30f, D2 = 1e30f;
    int I0 = -1, I1 = -1, I2 = -1;
    for (int c2 = 0; c2 < 8; ++c2) {
#pragma unroll
      for (int k = 0; k < 3; ++k) {
        float d = cd[c2][tid][k];
        int i = ci[c2][tid][k];
        bool q0 = (d < D0) || (d == D0 && i < I0);
        bool q1 = (d < D1) || (d == D1 && i < I1);
        bool q2 = (d < D2) || (d == D2 && i < I2);
        if (q0)      { D2 = D1; I2 = I1; D1 = D0; I1 = I0; D0 = d; I0 = i; }
        else if (q1) { D2 = D1; I2 = I1; D1 = d;  I1 = i; }
        else if (q2) { D2 = d;  I2 = i; }
      }
    }
    float r0 = 1.0f / fmaxf(D0, 1e-8f);
    float r1 = 1.0f / fmaxf(D1, 1e-8f);
    float r2 = 1.0f / fmaxf(D2, 1e-8f);
    float rs = (r0 + r1) + r2;
    wsh[0][tid] = r0 / rs; wsh[1][tid] = r1 / rs; wsh[2][tid] = r2 / rs;
    ish[0][tid] = I0; ish[1][tid] = I1; ish[2][tid] = I2;
  }
  __syncthreads();

  // Interp/gather: 8 lanes per query, coalesced reads + 64B-line writes.
  int gq = tid >> 3, l = tid & 7;
  float w0 = wsh[0][gq], w1 = wsh[1][gq], w2 = wsh[2][gq];
  int qg2 = b * kN + n0 + gq;
  const float* fb = fea2t + ((size_t)b * kS) * kD2;
  const float* g0p = fb + (size_t)ish[0][gq] * kD2;
  const float* g1p = fb + (size_t)ish[1][gq] * kD2;
  const float* g2p = fb + (size_t)ish[2][gq] * kD2;
  unsigned short* op = XT + (size_t)qg2 * kKX + kD1;  // cols 128..383
#pragma unroll
  for (int k = 0; k < 8; ++k) {
    int c = (l + 8 * k) * 4;
    float4 f0 = *(const float4*)(g0p + c);
    float4 f1 = *(const float4*)(g1p + c);
    float4 f2 = *(const float4*)(g2p + c);
    unsigned short h[4];
    h[0] = f2bf((w0 * f0.x + w1 * f1.x) + w2 * f2.x);
    h[1] = f2bf((w0 * f0.y + w1 * f1.y) + w2 * f2.y);
    h[2] = f2bf((w0 * f0.z + w1 * f1.z) + w2 * f2.z);
    h[3] = f2bf((w0 * f0.w + w1 * f1.w) + w2 * f2.w);
    *(uint2*)(op + c) = *(uint2*)h;
  }
}

// Layer-0 GEMM. A and B both staged via cp16_async from bf16 sources with
// chunk-swizzled global columns (conflict-free ds_read_b128; no pad, no reg
// round-trip). Writes X1pre[j][o] bf16 (LDS-transposed) + transposed
// per-block BN partials (no atomics).
__global__ __launch_bounds__(256) void gemm0t_kernel(
    const unsigned short* __restrict__ Wbf, const unsigned short* __restrict__ Bt,
    const float* __restrict__ bias, unsigned short* __restrict__ X1pre,
    float* __restrict__ partS, float* __restrict__ partQ) {
  constexpr int KDIM = kKX;
  __shared__ unsigned short smem[9216];   // As[4096] + Bs[4096]; T-reuse needs 9216
  unsigned short* As = smem;
  unsigned short* Bs = smem + 4096;
  __shared__ float psum[2][128], pq[2][128];
  int tid = threadIdx.x;
  int j0 = blockIdx.x * 128;
  int m0 = blockIdx.y * 128;
  int w = tid >> 6, lane = tid & 63;
  int wm = w & 1, wn = w >> 1;
  int quad = lane >> 4, l16 = lane & 15;
  int brow = tid >> 2, bch = tid & 3;
  int qs = bch ^ ((brow & 3) ^ ((brow >> 2) & 3));   // staging source column
  int qsw = quad ^ ((l16 & 3) ^ ((l16 >> 2) & 3));   // reader chunk column

  // runtime C/D layout probe
  bf16x8 pone, pm;
#pragma unroll
  for (int i = 0; i < 8; ++i) { pone[i] = (__bf16)1.0f; pm[i] = (__bf16)(float)l16; }
  f32x4 zf = {};
  f32x4 dr = __builtin_amdgcn_mfma_f32_16x16x32_bf16(pm, pone, zf, 0, 0, 0);
  f32x4 dc = __builtin_amdgcn_mfma_f32_16x16x32_bf16(pone, pm, zf, 0, 0, 0);
  int rowv[4], colv[4];
#pragma unroll
  for (int r = 0; r < 4; ++r) {
    rowv[r] = (int)(dr[r] * (1.0f / 32.0f) + 0.5f);
    colv[r] = (int)(dc[r] * (1.0f / 32.0f) + 0.5f);
  }

  f32x4 acc[4][4] = {};
  for (int k0 = 0; k0 < KDIM; k0 += 32) {
    cp16_async(Bt + (size_t)(j0 + brow) * KDIM + k0 + qs * 8, &Bs[(size_t)tid * 8]);
    cp16_async(Bt + (size_t)(j0 + 64 + brow) * KDIM + k0 + qs * 8, &Bs[(size_t)(tid + 256) * 8]);
    cp16_async(Wbf + (size_t)(m0 + brow) * KDIM + k0 + qs * 8, &As[(size_t)tid * 8]);
    cp16_async(Wbf + (size_t)(m0 + 64 + brow) * KDIM + k0 + qs * 8, &As[(size_t)(tid + 256) * 8]);
    __syncthreads();
    bf16x8 af[4], bfr[4];
#pragma unroll
    for (int mt = 0; mt < 4; ++mt)
      af[mt] = *(const bf16x8*)(&As[(wm * 64 + mt * 16 + l16) * 32 + qsw * 8]);
#pragma unroll
    for (int nt = 0; nt < 4; ++nt)
      bfr[nt] = *(const bf16x8*)(&Bs[(wn * 64 + nt * 16 + l16) * 32 + qsw * 8]);
#pragma unroll
    for (int mt = 0; mt < 4; ++mt)
#pragma unroll
      for (int nt = 0; nt < 4; ++nt)
        acc[mt][nt] = __builtin_amdgcn_mfma_f32_16x16x32_bf16(af[mt], bfr[nt], acc[mt][nt], 0, 0, 0);
    __syncthreads();
  }

  // Epilogue: v = acc + bias; pack bf16 quads; per-(mt,r) stats reduce.
  uint2 h2[4][4];
#pragma unroll
  for (int mt = 0; mt < 4; ++mt) {
    int obase = m0 + wm * 64 + mt * 16 + rowv[0];
    float4 bv4 = *(const float4*)&bias[obase];
    float s4[4] = {0.f, 0.f, 0.f, 0.f}, q4[4] = {0.f, 0.f, 0.f, 0.f};
#pragma unroll
    for (int nt = 0; nt < 4; ++nt) {
      unsigned short hh[4];
#pragma unroll
      for (int r = 0; r < 4; ++r) {
        float v = acc[mt][nt][r] + ((const float*)&bv4)[r];
        s4[r] += v; q4[r] += v * v;
        hh[r] = f2bf(v);
      }
      h2[mt][nt] = *(uint2*)hh;
    }
#pragma unroll
    for (int r = 0; r < 4; ++r) {
      float s = s4[r], qq = q4[r];
#pragma unroll
      for (int d2 = 1; d2 < 16; d2 <<= 1) {
        s += __shfl_xor(s, d2, 64);
        qq += __shfl_xor(qq, d2, 64);
      }
      if (l16 == 0) {
        int ol = wm * 64 + mt * 16 + rowv[0] + r;
        psum[wn][ol] = s;
        pq[wn][ol] = qq;
      }
    }
  }

  // Transposed store in two wave-rounds through the dead As/Bs LDS.
  unsigned short* T = smem + wm * 4608;  // 64*72
  int jr = lane >> 3, cc = lane & 7;
  if (wn == 0) {
#pragma unroll
    for (int mt = 0; mt < 4; ++mt)
#pragma unroll
      for (int nt = 0; nt < 4; ++nt)
        *(uint2*)&T[(nt * 16 + colv[0]) * 72 + mt * 16 + rowv[0]] = h2[mt][nt];
#pragma unroll
    for (int it = 0; it < 8; ++it) {
      int jl = it * 8 + jr;
      uint4 u = *(uint4*)&T[jl * 72 + cc * 8];
      *(uint4*)&X1pre[(size_t)(j0 + jl) * kCO + m0 + wm * 64 + cc * 8] = u;
    }
  }
  __syncthreads();
  if (wn == 1) {
#pragma unroll
    for (int mt = 0; mt < 4; ++mt)
#pragma unroll
      for (int nt = 0; nt < 4; ++nt)
        *(uint2*)&T[(nt * 16 + colv[0]) * 72 + mt * 16 + rowv[0]] = h2[mt][nt];
#pragma unroll
    for (int it = 0; it < 8; ++it) {
      int jl = it * 8 + jr;
      uint4 u = *(uint4*)&T[jl * 72 + cc * 8];
      *(uint4*)&X1pre[(size_t)(j0 + 64 + jl) * kCO + m0 + wm * 64 + cc * 8] = u;
    }
  }
  if (tid < 128) {
    float ss = psum[0][tid] + psum[1][tid];
    float qq = pq[0][tid] + pq[1][tid];
    partS[(size_t)(m0 + tid) * 512 + blockIdx.x] = ss;
    partQ[(size_t)(m0 + tid) * 512 + blockIdx.x] = qq;
  }
}

// Reduce per-block partials (part[o][512], contiguous) -> BN affine coefs.
__global__ __launch_bounds__(64) void redstats_kernel(
    const float* __restrict__ pS, const float* __restrict__ pQ,
    const float* __restrict__ gamma, const float* __restrict__ beta,
    float* __restrict__ ab) {
  int o = blockIdx.x, t = threadIdx.x;
  float s = 0.f, q = 0.f;
  for (int i = t; i < 512; i += 64) {
    s += pS[(size_t)o * 512 + i];
    q += pQ[(size_t)o * 512 + i];
  }
#pragma unroll
  for (int d = 1; d < 64; d <<= 1) {
    s += __shfl_xor(s, d, 64);
    q += __shfl_xor(q, d, 64);
  }
  if (t == 0) {
    float m = s * (1.0f / 65536.f);
    float var = q * (1.0f / 65536.f) - m * m;
    float rsq = 1.0f / sqrtf(var + 1e-5f);
    float a = gamma[o] * rsq;
    ab[o] = a;
    ab[kCO + o] = beta[o] - m * a;
  }
}

// Layer-1 GEMM. A via cp16_async (swizzled source); B reg-staged with inline
// BN affine + ReLU (r8 showed this VALU hides under latency -- keep inline),
// source column swizzled, LDS write linear. Conflict-free fragment reads.
// Epilogue writes fp32 out [b][o][n] + transposed per-block partials.
__global__ __launch_bounds__(256) void gemm1f_kernel(
    const unsigned short* __restrict__ Wbf, const unsigned short* __restrict__ Xp,
    const float* __restrict__ bias, const float* __restrict__ ab0,
    float* __restrict__ out, float* __restrict__ partS, float* __restrict__ partQ) {
  constexpr int KDIM = kCO;
  __shared__ unsigned short As[4096];
  __shared__ unsigned short Bs[4096];
  __shared__ float Acf[256], Ccf[256];
  __shared__ float psum[2][128], pq[2][128];
  int tid = threadIdx.x;
  int j0 = blockIdx.x * 128;
  int m0 = blockIdx.y * 128;
  int w = tid >> 6, lane = tid & 63;
  int wm = w & 1, wn = w >> 1;
  int quad = lane >> 4, l16 = lane & 15;
  int brow = tid >> 2, bch = tid & 3;
  int qs = bch ^ ((brow & 3) ^ ((brow >> 2) & 3));
  int qsw = quad ^ ((l16 & 3) ^ ((l16 >> 2) & 3));

  if (tid < 256) { Acf[tid] = ab0[tid]; Ccf[tid] = ab0[kCO + tid]; }

  bf16x8 pone, pm;
#pragma unroll
  for (int i = 0; i < 8; ++i) { pone[i] = (__bf16)1.0f; pm[i] = (__bf16)(float)l16; }
  f32x4 zf = {};
  f32x4 dr = __builtin_amdgcn_mfma_f32_16x16x32_bf16(pm, pone, zf, 0, 0, 0);
  f32x4 dc = __builtin_amdgcn_mfma_f32_16x16x32_bf16(pone, pm, zf, 0, 0, 0);
  int rowv[4], colv[4];
#pragma unroll
  for (int r = 0; r < 4; ++r) {
    rowv[r] = (int)(dr[r] * (1.0f / 32.0f) + 0.5f);
    colv[r] = (int)(dc[r] * (1.0f / 32.0f) + 0.5f);
  }
  __syncthreads();  // Acf/Ccf visible before first staging use

  f32x4 acc[4][4] = {};
  for (int k0 = 0; k0 < KDIM; k0 += 32) {
    {
      int cb = k0 + qs * 8;
      float4 a0 = *(const float4*)&Acf[cb];
      float4 a1 = *(const float4*)&Acf[cb + 4];
      float4 c0 = *(const float4*)&Ccf[cb];
      float4 c1 = *(const float4*)&Ccf[cb + 4];
#pragma unroll
      for (int h = 0; h < 2; ++h) {
        uint4 raw = *(const uint4*)(Xp + (size_t)(j0 + h * 64 + brow) * kCO + cb);
        const unsigned short* rs = (const unsigned short*)&raw;
        unsigned short o8[8];
        o8[0] = f2bf(fmaxf(fmaf(a0.x, bf2f(rs[0]), c0.x), 0.f));
        o8[1] = f2bf(fmaxf(fmaf(a0.y, bf2f(rs[1]), c0.y), 0.f));
        o8[2] = f2bf(fmaxf(fmaf(a0.z, bf2f(rs[2]), c0.z), 0.f));
        o8[3] = f2bf(fmaxf(fmaf(a0.w, bf2f(rs[3]), c0.w), 0.f));
        o8[4] = f2bf(fmaxf(fmaf(a1.x, bf2f(rs[4]), c1.x), 0.f));
        o8[5] = f2bf(fmaxf(fmaf(a1.y, bf2f(rs[5]), c1.y), 0.f));
        o8[6] = f2bf(fmaxf(fmaf(a1.z, bf2f(rs[6]), c1.z), 0.f));
        o8[7] = f2bf(fmaxf(fmaf(a1.w, bf2f(rs[7]), c1.w), 0.f));
        *(uint4*)&Bs[(size_t)(tid + h * 256) * 8] = *(uint4*)o8;
      }
    }
    cp16_async(Wbf + (size_t)(m0 + brow) * KDIM + k0 + qs * 8, &As[(size_t)tid * 8]);
    cp16_async(Wbf + (size_t)(m0 + 64 + brow) * KDIM + k0 + qs * 8, &As[(size_t)(tid + 256) * 8]);
    __syncthreads();
    bf16x8 af[4], bfr[4];
#pragma unroll
    for (int mt = 0; mt < 4; ++mt)
      af[mt] = *(const bf16x8*)(&As[(wm * 64 + mt * 16 + l16) * 32 + qsw * 8]);
#pragma unroll
    for (int nt = 0; nt < 4; ++nt)
      bfr[nt] = *(const bf16x8*)(&Bs[(wn * 64 + nt * 16 + l16) * 32 + qsw * 8]);
#pragma unroll
    for (int mt = 0; mt < 4; ++mt)
#pragma unroll
      for (int nt = 0; nt < 4; ++nt)
        acc[mt][nt] = __builtin_amdgcn_mfma_f32_16x16x32_bf16(af[mt], bfr[nt], acc[mt][nt], 0, 0, 0);
    __syncthreads();
  }

#pragma unroll
  for (int mt = 0; mt < 4; ++mt) {
#pragma unroll
    for (int r = 0; r < 4; ++r) {
      int ol = wm * 64 + mt * 16 + rowv[r];
      int o = m0 + ol;
      float bv = bias[o];
      float s = 0.f, qq = 0.f;
#pragma unroll
      for (int nt = 0; nt < 4; ++nt) {
        int j = j0 + wn * 64 + nt * 16 + colv[r];
        float v = acc[mt][nt][r] + bv;
        s += v; qq += v * v;
        int bb = j >> 14, nn = j & (kN - 1);
        out[((size_t)(bb * kCO + o)) * kN + nn] = v;
      }
#pragma unroll
      for (int d2 = 1; d2 < 16; d2 <<= 1) {
        s += __shfl_xor(s, d2, 64);
        qq += __shfl_xor(qq, d2, 64);
      }
      if (l16 == 0) {
        psum[wn][ol] = s;
        pq[wn][ol] = qq;
      }
    }
  }
  __syncthreads();
  if (tid < 128) {
    float ss = psum[0][tid] + psum[1][tid];
    float qq = pq[0][tid] + pq[1][tid];
    partS[(size_t)(m0 + tid) * 512 + blockIdx.x] = ss;
    partQ[(size_t)(m0 + tid) * 512 + blockIdx.x] = qq;
  }
}

// Final BN+ReLU with inlined stats reduction: each block spans 1024 elements
// of a single channel o; reduces part[o][0..512) (contiguous, L2-hot) and
// applies the affine in one pass.
__global__ __launch_bounds__(256) void finalf_kernel(
    float* __restrict__ Y, const float* __restrict__ pS,
    const float* __restrict__ pQ, const float* __restrict__ gamma,
    const float* __restrict__ beta) {
  __shared__ float sw[4], qw[4], coef[2];
  size_t base = (size_t)blockIdx.x * 1024;
  int o = (int)((base >> 14) & (kCO - 1));
  int tid = threadIdx.x;
  float s = pS[(size_t)o * 512 + tid] + pS[(size_t)o * 512 + 256 + tid];
  float q = pQ[(size_t)o * 512 + tid] + pQ[(size_t)o * 512 + 256 + tid];
#pragma unroll
  for (int d = 1; d < 64; d <<= 1) {
    s += __shfl_xor(s, d, 64);
    q += __shfl_xor(q, d, 64);
  }
  if ((tid & 63) == 0) { sw[tid >> 6] = s; qw[tid >> 6] = q; }
  __syncthreads();
  if (tid == 0) {
    float st = (sw[0] + sw[1]) + (sw[2] + sw[3]);
    float qt = (qw[0] + qw[1]) + (qw[2] + qw[3]);
    float m = st * (1.0f / 65536.f);
    float var = qt * (1.0f / 65536.f) - m * m;
    float rsq = 1.0f / sqrtf(var + 1e-5f);
    float a = gamma[o] * rsq;
    coef[0] = a;
    coef[1] = beta[o] - m * a;
  }
  __syncthreads();
  float a = coef[0], c = coef[1];
  float4 u = *(float4*)(Y + base + tid * 4);
  float* t = (float*)&u;
#pragma unroll
  for (int k = 0; k < 4; ++k) t[k] = fmaxf(fmaf(a, t[k], c), 0.0f);
  *(float4*)(Y + base + tid * 4) = u;
}

}  // namespace

extern "C" void kernel_launch(void* const* d_in, const int* in_sizes, int n_in,
                              void* d_out, int out_size, void* d_ws, size_t ws_size,
                              hipStream_t stream) {
  const float* xyz1 = (const float*)d_in[0];
  const float* xyz2 = (const float*)d_in[1];
  const float* fea1 = (const float*)d_in[2];
  const float* fea2 = (const float*)d_in[3];
  const float* W0 = (const float*)d_in[4];
  const float* b0 = (const float*)d_in[5];
  const float* g0 = (const float*)d_in[6];
  const float* be0 = (const float*)d_in[7];
  const float* W1 = (const float*)d_in[8];
  const float* b1 = (const float*)d_in[9];
  const float* g1 = (const float*)d_in[10];
  const float* be1 = (const float*)d_in[11];
  float* out = (float*)d_out;

  char* ws = (char*)d_ws;
  float4* pts4 = (float4*)ws;
  float* ab0 = (float*)(ws + kOffAb0);
  unsigned short* X1pre = (unsigned short*)(ws + kOffX1p);
  float* partS = (float*)(ws + kOffPart);
  float* partQ = (float*)(ws + kOffPart + 524288);
  float* fea2t = (float*)(ws + kOffPart);          // overlays partials, dead after knn
  unsigned short* W0bf = (unsigned short*)(ws + kOffWbf);
  unsigned short* W1bf = (unsigned short*)(ws + kOffW1bf);
  unsigned short* XT = (unsigned short*)d_out;     // bf16 [65536][384], dead after gemm0

  if (ws_size < kOffW1bf + (size_t)kCO * kCO * 2) return;

  prep_kernel<<<2152, 256, 0, stream>>>(xyz2, pts4, fea2, fea2t, fea1, XT,
                                        W0, W1, W0bf, W1bf);
  knn_interp_kernel<<<kNCOL / 64, 512, 0, stream>>>(xyz1, pts4, fea2t, XT);
  gemm0t_kernel<<<dim3(kNCOL / 128, kCO / 128), 256, 0, stream>>>(W0bf, XT, b0, X1pre, partS, partQ);
  redstats_kernel<<<kCO, 64, 0, stream>>>(partS, partQ, g0, be0, ab0);
  gemm1f_kernel<<<dim3(kNCOL / 128, kCO / 128), 256, 0, stream>>>(W1bf, X1pre, b1, ab0, out, partS, partQ);
  finalf_kernel<<<kCO * kNCOL / (256 * 4), 256, 0, stream>>>(out, partS, partQ, g1, be1);
}

// Round 10
// 335.693 us; speedup vs baseline: 1.0324x; 1.0059x over previous
//
#include <hip/hip_runtime.h>
#include <math.h>

namespace {

constexpr int kB = 4;
constexpr int kN = 16384;
constexpr int kS = 4096;
constexpr int kD1 = 128;
constexpr int kD2 = 256;
constexpr int kCO = 256;
constexpr int kNCOL = kB * kN;   // 65536
constexpr int kKX = kD1 + kD2;   // 384, XT row stride

// ws layout (known-good bound 67375104 B):
//   pts4  @ 0         float4[16384]          262144 B
//   ab0   @ 262144    float[512]
//   X1pre @ 266240    bf16 [65536][256]      33554432 B  (pre-BN layer-0 out, j-major)
//   partS @ 33820672  fp32 [256][512]        524288 B    } fea2t fp32 16MB overlays
//   partQ @ 34344960  fp32 [256][512]        524288 B    } [kOffPart,kOffWbf) til knn done
//   W0bf  @ 50597888  bf16 [256][384]        196608 B    (starts exactly at fea2t end)
//   W1bf  @ 50794496  bf16 [256][256]        131072 B    (end 50925568)
constexpr size_t kOffAb0  = 262144;
constexpr size_t kOffX1p  = 266240;
constexpr size_t kOffPart = 33820672;
constexpr size_t kOffWbf  = 50597888;   // = kOffPart + 16MB (fea2t size)
constexpr size_t kOffW1bf = 50794496;
// out buffer doubles as XT bf16 [65536][384] (50.3MB) until gemm1 writes out.

typedef __bf16 bf16x8 __attribute__((ext_vector_type(8)));
typedef float f32x4 __attribute__((ext_vector_type(4)));

__device__ __forceinline__ float bf2f(unsigned short u) {
  unsigned int x = ((unsigned int)u) << 16;
  float f;
  __builtin_memcpy(&f, &x, 4);
  return f;
}
__device__ __forceinline__ unsigned short f2bf(float f) {
  unsigned int x;
  __builtin_memcpy(&x, &f, 4);
  x += 0x7fffu + ((x >> 16) & 1u);  // RNE
  return (unsigned short)(x >> 16);
}

__device__ __forceinline__ void cp16_async(const void* g, void* l) {
#if __has_builtin(__builtin_amdgcn_global_load_lds)
  __builtin_amdgcn_global_load_lds(
      (const __attribute__((address_space(1))) unsigned int*)g,
      (__attribute__((address_space(3))) unsigned int*)l, 16, 0, 0);
#else
  *(uint4*)l = *(const uint4*)g;
#endif
}

// LDS chunk swizzle (r9, kept): 16B chunk slot (row, q) holds global column
// q ^ xr(row), xr(row) = (row&3) ^ ((row>>2)&3); readers fetch quad^xr(row).
// 2-way bank access = free (m136). Source-side permutation only (G21).
//
// r10: DOUBLE-BUFFERED K-loop, ONE barrier per K-step. The old structure
// (stage -> barrier -> compute -> barrier) exposed full load latency every
// K-step (12/8 steps, latency-bound: r9's conflict fix only moved -4us).
// Now tile k+1 is issued before compute of tile k; the single barrier's
// vmcnt(0) drain lands after the MFMA/ds_read issue -> latency overlapped,
// barrier count halved. Safe: buf^1's readers finished at the prior barrier.

// Fused front-end, 4 block segments:
//   [0,1024):    fea2 [b][c][s] -> fea2t [b][s][c] fp32 (64x64 LDS tiles)
//   [1024,1088): xyz2 -> pts4 {2x,2y,2z,|p|^2}
//   [1088,2112): fea1 [b][c][n] -> XT[j][0..127] bf16
//   [2112,2152): W0,W1 fp32 -> bf16 (RNE, bit-identical to in-GEMM cvt)
__global__ __launch_bounds__(256) void prep_kernel(
    const float* __restrict__ xyz2, float4* __restrict__ pts4,
    const float* __restrict__ fea2, float* __restrict__ fea2t,
    const float* __restrict__ fea1, unsigned short* __restrict__ XT,
    const float* __restrict__ W0, const float* __restrict__ W1,
    unsigned short* __restrict__ W0bf, unsigned short* __restrict__ W1bf) {
#pragma clang fp contract(off)
  __shared__ __align__(16) char lds_raw[33024];
  int bid = blockIdx.x;
  int t = threadIdx.x;
  if (bid >= 2112) {
    int gt = (bid - 2112) * 256 + t;
    int base = gt * 16;
    const float* src;
    unsigned short* dst;
    if (base < kCO * kKX) {
      src = W0 + base;
      dst = W0bf + base;
    } else {
      src = W1 + (base - kCO * kKX);
      dst = W1bf + (base - kCO * kKX);
    }
    float4 f0 = *(const float4*)(src);
    float4 f1 = *(const float4*)(src + 4);
    float4 f2 = *(const float4*)(src + 8);
    float4 f3 = *(const float4*)(src + 12);
    unsigned short h[16] = {f2bf(f0.x), f2bf(f0.y), f2bf(f0.z), f2bf(f0.w),
                            f2bf(f1.x), f2bf(f1.y), f2bf(f1.z), f2bf(f1.w),
                            f2bf(f2.x), f2bf(f2.y), f2bf(f2.z), f2bf(f2.w),
                            f2bf(f3.x), f2bf(f3.y), f2bf(f3.z), f2bf(f3.w)};
    ((uint4*)dst)[0] = ((uint4*)h)[0];
    ((uint4*)dst)[1] = ((uint4*)h)[1];
    return;
  }
  if (bid >= 1024 && bid < 1088) {
    int i = (bid - 1024) * 256 + t;
    float x = xyz2[i * 3 + 0];
    float y = xyz2[i * 3 + 1];
    float z = xyz2[i * 3 + 2];
    float4 p;
    p.w = (x * x + y * y) + z * z;
    p.x = x + x; p.y = y + y; p.z = z + z;
    pts4[i] = p;
    return;
  }
  if (bid < 1024) {
    float (*T)[65] = (float (*)[65])lds_raw;
    int s0 = (bid & 63) * 64;
    int c0 = ((bid >> 6) & 3) * 64;
    int b = bid >> 8;
    {
      int sl = t & 63, cg2 = t >> 6;
#pragma unroll
      for (int i = 0; i < 16; ++i) {
        int cl = cg2 * 16 + i;
        T[sl][cl] = fea2[((size_t)(b * kD2 + c0 + cl)) * kS + s0 + sl];
      }
    }
    __syncthreads();
    {
      int cl = t & 63, sg = t >> 6;
#pragma unroll
      for (int i = 0; i < 16; ++i) {
        int sl = sg * 16 + i;
        fea2t[((size_t)(b * kS + s0 + sl)) * kD2 + c0 + cl] = T[sl][cl];
      }
    }
    return;
  }
  // fea1 transpose segment
  {
    float (*T)[129] = (float (*)[129])lds_raw;
    int fb = bid - 1088;
    int n0 = (fb & 255) * 64;
    int b = fb >> 8;
    {
      int nl = t & 63, cg2 = t >> 6;  // cg2 0..3
#pragma unroll
      for (int i = 0; i < 32; ++i) {
        int c = cg2 * 32 + i;
        T[nl][c] = fea1[((size_t)(b * kD1 + c)) * kN + n0 + nl];
      }
    }
    __syncthreads();
    {
      int nl = t >> 2, ch = t & 3;  // 32 channels per thread
      unsigned short h[32];
#pragma unroll
      for (int i = 0; i < 32; ++i) h[i] = f2bf(T[nl][ch * 32 + i]);
      uint4* dst = (uint4*)&XT[(size_t)(b * kN + n0 + nl) * kKX + ch * 32];
#pragma unroll
      for (int i = 0; i < 4; ++i) dst[i] = ((uint4*)h)[i];
    }
  }
}

// Block = 512 threads = 64 queries x 8 chunks of 512 points (round-3 form:
// 13.8KB LDS, occupancy 66%, VALU-bound 87% -- do NOT grow this kernel's
// LDS/barrier footprint; r4's fused transpose cost +20us).
__global__ __launch_bounds__(512) void knn_interp_kernel(
    const float* __restrict__ xyz1, const float4* __restrict__ pts4,
    const float* __restrict__ fea2t, unsigned short* __restrict__ XT) {
#pragma clang fp contract(off)
  __shared__ float cd[8][64][3];
  __shared__ int ci[8][64][3];
  __shared__ float wsh[3][64];
  __shared__ int ish[3][64];
  int tid = threadIdx.x;
  int q = tid & 63;
  int chunk = __builtin_amdgcn_readfirstlane(tid >> 6);  // 0..7, wave-uniform
  int b = blockIdx.x >> 8;                 // scalar (256 blocks per batch)
  int n0 = (blockIdx.x & 255) * 64;        // scalar
  int n = n0 + q;
  int qg = b * kN + n;

  const float* p1 = xyz1 + (size_t)qg * 3;
  float x = p1[0], y = p1[1], z = p1[2];
  float n1 = (x * x + y * y) + z * z;

  const float4* pp = pts4 + b * kS + chunk * 512;  // scalar base
  int sbase = chunk * 512;
  float d0v = 1e30f, d1v = 1e30f, d2v = 1e30f;
  int i0 = 0, i1 = 0, i2 = 0;
  for (int s = 0; s < 512; s += 4) {
    float4 P[4];
    P[0] = pp[s]; P[1] = pp[s + 1]; P[2] = pp[s + 2]; P[3] = pp[s + 3];
#pragma unroll
    for (int u = 0; u < 4; ++u) {
      float dot2 = (x * P[u].x + y * P[u].y) + z * P[u].z;
      float d = (n1 + P[u].w) - dot2;
      if (__ballot(d < d2v)) {  // wave-uniform skip of the insert
        int si = sbase + s + u;
        bool b0 = d < d0v, b1 = d < d1v, b2 = d < d2v;
        int i2n = b1 ? i1 : (b2 ? si : i2);
        int i1n = b0 ? i0 : (b1 ? si : i1);
        int i0n = b0 ? si : i0;
        d2v = __builtin_amdgcn_fmed3f(d1v, d, d2v);
        d1v = __builtin_amdgcn_fmed3f(d0v, d, d1v);
        d0v = fminf(d0v, d);
        i0 = i0n; i1 = i1n; i2 = i2n;
      }
    }
  }
  cd[chunk][q][0] = d0v; cd[chunk][q][1] = d1v; cd[chunk][q][2] = d2v;
  ci[chunk][q][0] = i0;  ci[chunk][q][1] = i1;  ci[chunk][q][2] = i2;
  __syncthreads();

  if (tid < 64) {
    float D0 = 1e30f, D1 = 1e30f, D2 = 1e30f;
    int I0 = -1, I1 = -1, I2 = -1;
    for (int c2 = 0; c2 < 8; ++c2) {
#pragma unroll
      for (int k = 0; k < 3; ++k) {
        float d = cd[c2][tid][k];
        int i = ci[c2][tid][k];
        bool q0 = (d < D0) || (d == D0 && i < I0);
        bool q1 = (d < D1) || (d == D1 && i < I1);
        bool q2 = (d < D2) || (d == D2 && i < I2);
        if (q0)      { D2 = D1; I2 = I1; D1 = D0; I1 = I0; D0 = d; I0 = i; }
        else if (q1) { D2 = D1; I2 = I1; D1 = d;  I1 = i; }
        else if (q2) { D2 = d;  I2 = i; }
      }
    }
    float r0 = 1.0f / fmaxf(D0, 1e-8f);
    float r1 = 1.0f / fmaxf(D1, 1e-8f);
    float r2 = 1.0f / fmaxf(D2, 1e-8f);
    float rs = (r0 + r1) + r2;
    wsh[0][tid] = r0 / rs; wsh[1][tid] = r1 / rs; wsh[2][tid] = r2 / rs;
    ish[0][tid] = I0; ish[1][tid] = I1; ish[2][tid] = I2;
  }
  __syncthreads();

  // Interp/gather: 8 lanes per query, coalesced reads + 64B-line writes.
  int gq = tid >> 3, l = tid & 7;
  float w0 = wsh[0][gq], w1 = wsh[1][gq], w2 = wsh[2][gq];
  int qg2 = b * kN + n0 + gq;
  const float* fb = fea2t + ((size_t)b * kS) * kD2;
  const float* g0p = fb + (size_t)ish[0][gq] * kD2;
  const float* g1p = fb + (size_t)ish[1][gq] * kD2;
  const float* g2p = fb + (size_t)ish[2][gq] * kD2;
  unsigned short* op = XT + (size_t)qg2 * kKX + kD1;  // cols 128..383
#pragma unroll
  for (int k = 0; k < 8; ++k) {
    int c = (l + 8 * k) * 4;
    float4 f0 = *(const float4*)(g0p + c);
    float4 f1 = *(const float4*)(g1p + c);
    float4 f2 = *(const float4*)(g2p + c);
    unsigned short h[4];
    h[0] = f2bf((w0 * f0.x + w1 * f1.x) + w2 * f2.x);
    h[1] = f2bf((w0 * f0.y + w1 * f1.y) + w2 * f2.y);
    h[2] = f2bf((w0 * f0.z + w1 * f1.z) + w2 * f2.z);
    h[3] = f2bf((w0 * f0.w + w1 * f1.w) + w2 * f2.w);
    *(uint2*)(op + c) = *(uint2*)h;
  }
}

// Layer-0 GEMM, double-buffered K-loop (1 barrier/step). A and B staged via
// cp16_async with chunk-swizzled source columns (conflict-free ds_read_b128).
// Writes X1pre[j][o] bf16 (LDS-transposed) + transposed per-block partials.
__global__ __launch_bounds__(256) void gemm0t_kernel(
    const unsigned short* __restrict__ Wbf, const unsigned short* __restrict__ Bt,
    const float* __restrict__ bias, unsigned short* __restrict__ X1pre,
    float* __restrict__ partS, float* __restrict__ partQ) {
  constexpr int KDIM = kKX;
  __shared__ unsigned short smem[16384];  // 2 x (As[4096]+Bs[4096]); T reuse
  __shared__ float psum[2][128], pq[2][128];
  int tid = threadIdx.x;
  int j0 = blockIdx.x * 128;
  int m0 = blockIdx.y * 128;
  int w = tid >> 6, lane = tid & 63;
  int wm = w & 1, wn = w >> 1;
  int quad = lane >> 4, l16 = lane & 15;
  int brow = tid >> 2, bch = tid & 3;
  int qs = bch ^ ((brow & 3) ^ ((brow >> 2) & 3));   // staging source column
  int qsw = quad ^ ((l16 & 3) ^ ((l16 >> 2) & 3));   // reader chunk column

  // runtime C/D layout probe
  bf16x8 pone, pm;
#pragma unroll
  for (int i = 0; i < 8; ++i) { pone[i] = (__bf16)1.0f; pm[i] = (__bf16)(float)l16; }
  f32x4 zf = {};
  f32x4 dr = __builtin_amdgcn_mfma_f32_16x16x32_bf16(pm, pone, zf, 0, 0, 0);
  f32x4 dc = __builtin_amdgcn_mfma_f32_16x16x32_bf16(pone, pm, zf, 0, 0, 0);
  int rowv[4], colv[4];
#pragma unroll
  for (int r = 0; r < 4; ++r) {
    rowv[r] = (int)(dr[r] * (1.0f / 32.0f) + 0.5f);
    colv[r] = (int)(dc[r] * (1.0f / 32.0f) + 0.5f);
  }

  // prologue: stage K-step 0 into buffer 0
  cp16_async(Wbf + (size_t)(m0 + brow) * KDIM + qs * 8, &smem[(size_t)tid * 8]);
  cp16_async(Wbf + (size_t)(m0 + 64 + brow) * KDIM + qs * 8, &smem[(size_t)(tid + 256) * 8]);
  cp16_async(Bt + (size_t)(j0 + brow) * KDIM + qs * 8, &smem[4096 + (size_t)tid * 8]);
  cp16_async(Bt + (size_t)(j0 + 64 + brow) * KDIM + qs * 8, &smem[4096 + (size_t)(tid + 256) * 8]);
  __syncthreads();

  f32x4 acc[4][4] = {};
  int cur = 0;
  for (int k0 = 0; k0 < KDIM; k0 += 32) {
    unsigned short* As = smem + cur * 8192;
    unsigned short* Bs = As + 4096;
    int kn = k0 + 32;
    if (kn < KDIM) {  // prefetch next tile into the other buffer
      unsigned short* An = smem + (cur ^ 1) * 8192;
      unsigned short* Bn = An + 4096;
      cp16_async(Wbf + (size_t)(m0 + brow) * KDIM + kn + qs * 8, &An[(size_t)tid * 8]);
      cp16_async(Wbf + (size_t)(m0 + 64 + brow) * KDIM + kn + qs * 8, &An[(size_t)(tid + 256) * 8]);
      cp16_async(Bt + (size_t)(j0 + brow) * KDIM + kn + qs * 8, &Bn[(size_t)tid * 8]);
      cp16_async(Bt + (size_t)(j0 + 64 + brow) * KDIM + kn + qs * 8, &Bn[(size_t)(tid + 256) * 8]);
    }
    bf16x8 af[4], bfr[4];
#pragma unroll
    for (int mt = 0; mt < 4; ++mt)
      af[mt] = *(const bf16x8*)(&As[(wm * 64 + mt * 16 + l16) * 32 + qsw * 8]);
#pragma unroll
    for (int nt = 0; nt < 4; ++nt)
      bfr[nt] = *(const bf16x8*)(&Bs[(wn * 64 + nt * 16 + l16) * 32 + qsw * 8]);
#pragma unroll
    for (int mt = 0; mt < 4; ++mt)
#pragma unroll
      for (int nt = 0; nt < 4; ++nt)
        acc[mt][nt] = __builtin_amdgcn_mfma_f32_16x16x32_bf16(af[mt], bfr[nt], acc[mt][nt], 0, 0, 0);
    __syncthreads();   // drains prefetch (after compute issue) + guards buf reuse
    cur ^= 1;
  }

  // Epilogue: v = acc + bias; pack bf16 quads; per-(mt,r) stats reduce.
  uint2 h2[4][4];
#pragma unroll
  for (int mt = 0; mt < 4; ++mt) {
    int obase = m0 + wm * 64 + mt * 16 + rowv[0];
    float4 bv4 = *(const float4*)&bias[obase];
    float s4[4] = {0.f, 0.f, 0.f, 0.f}, q4[4] = {0.f, 0.f, 0.f, 0.f};
#pragma unroll
    for (int nt = 0; nt < 4; ++nt) {
      unsigned short hh[4];
#pragma unroll
      for (int r = 0; r < 4; ++r) {
        float v = acc[mt][nt][r] + ((const float*)&bv4)[r];
        s4[r] += v; q4[r] += v * v;
        hh[r] = f2bf(v);
      }
      h2[mt][nt] = *(uint2*)hh;
    }
#pragma unroll
    for (int r = 0; r < 4; ++r) {
      float s = s4[r], qq = q4[r];
#pragma unroll
      for (int d2 = 1; d2 < 16; d2 <<= 1) {
        s += __shfl_xor(s, d2, 64);
        qq += __shfl_xor(qq, d2, 64);
      }
      if (l16 == 0) {
        int ol = wm * 64 + mt * 16 + rowv[0] + r;
        psum[wn][ol] = s;
        pq[wn][ol] = qq;
      }
    }
  }

  // Transposed store in two wave-rounds through the dead staging LDS.
  unsigned short* T = smem + wm * 4608;  // 64*72
  int jr = lane >> 3, cc = lane & 7;
  if (wn == 0) {
#pragma unroll
    for (int mt = 0; mt < 4; ++mt)
#pragma unroll
      for (int nt = 0; nt < 4; ++nt)
        *(uint2*)&T[(nt * 16 + colv[0]) * 72 + mt * 16 + rowv[0]] = h2[mt][nt];
#pragma unroll
    for (int it = 0; it < 8; ++it) {
      int jl = it * 8 + jr;
      uint4 u = *(uint4*)&T[jl * 72 + cc * 8];
      *(uint4*)&X1pre[(size_t)(j0 + jl) * kCO + m0 + wm * 64 + cc * 8] = u;
    }
  }
  __syncthreads();
  if (wn == 1) {
#pragma unroll
    for (int mt = 0; mt < 4; ++mt)
#pragma unroll
      for (int nt = 0; nt < 4; ++nt)
        *(uint2*)&T[(nt * 16 + colv[0]) * 72 + mt * 16 + rowv[0]] = h2[mt][nt];
#pragma unroll
    for (int it = 0; it < 8; ++it) {
      int jl = it * 8 + jr;
      uint4 u = *(uint4*)&T[jl * 72 + cc * 8];
      *(uint4*)&X1pre[(size_t)(j0 + 64 + jl) * kCO + m0 + wm * 64 + cc * 8] = u;
    }
  }
  if (tid < 128) {
    float ss = psum[0][tid] + psum[1][tid];
    float qq = pq[0][tid] + pq[1][tid];
    partS[(size_t)(m0 + tid) * 512 + blockIdx.x] = ss;
    partQ[(size_t)(m0 + tid) * 512 + blockIdx.x] = qq;
  }
}

// Reduce per-block partials (part[o][512], contiguous) -> BN affine coefs.
__global__ __launch_bounds__(64) void redstats_kernel(
    const float* __restrict__ pS, const float* __restrict__ pQ,
    const float* __restrict__ gamma, const float* __restrict__ beta,
    float* __restrict__ ab) {
  int o = blockIdx.x, t = threadIdx.x;
  float s = 0.f, q = 0.f;
  for (int i = t; i < 512; i += 64) {
    s += pS[(size_t)o * 512 + i];
    q += pQ[(size_t)o * 512 + i];
  }
#pragma unroll
  for (int d = 1; d < 64; d <<= 1) {
    s += __shfl_xor(s, d, 64);
    q += __shfl_xor(q, d, 64);
  }
  if (t == 0) {
    float m = s * (1.0f / 65536.f);
    float var = q * (1.0f / 65536.f) - m * m;
    float rsq = 1.0f / sqrtf(var + 1e-5f);
    float a = gamma[o] * rsq;
    ab[o] = a;
    ab[kCO + o] = beta[o] - m * a;
  }
}

// Layer-1 GEMM, double-buffered K-loop (1 barrier/step). A via cp16_async;
// B reg-staged with inline BN affine + ReLU (r8: this VALU hides under
// latency) -- its global loads issue at iteration top and drain under the
// MFMA phase. Conflict-free fragment reads via chunk swizzle.
__global__ __launch_bounds__(256) void gemm1f_kernel(
    const unsigned short* __restrict__ Wbf, const unsigned short* __restrict__ Xp,
    const float* __restrict__ bias, const float* __restrict__ ab0,
    float* __restrict__ out, float* __restrict__ partS, float* __restrict__ partQ) {
  constexpr int KDIM = kCO;
  __shared__ unsigned short smem[16384];  // 2 x (As[4096]+Bs[4096])
  __shared__ float Acf[256], Ccf[256];
  __shared__ float psum[2][128], pq[2][128];
  int tid = threadIdx.x;
  int j0 = blockIdx.x * 128;
  int m0 = blockIdx.y * 128;
  int w = tid >> 6, lane = tid & 63;
  int wm = w & 1, wn = w >> 1;
  int quad = lane >> 4, l16 = lane & 15;
  int brow = tid >> 2, bch = tid & 3;
  int qs = bch ^ ((brow & 3) ^ ((brow >> 2) & 3));
  int qsw = quad ^ ((l16 & 3) ^ ((l16 >> 2) & 3));

  if (tid < 256) { Acf[tid] = ab0[tid]; Ccf[tid] = ab0[kCO + tid]; }

  bf16x8 pone, pm;
#pragma unroll
  for (int i = 0; i < 8; ++i) { pone[i] = (__bf16)1.0f; pm[i] = (__bf16)(float)l16; }
  f32x4 zf = {};
  f32x4 dr = __builtin_amdgcn_mfma_f32_16x16x32_bf16(pm, pone, zf, 0, 0, 0);
  f32x4 dc = __builtin_amdgcn_mfma_f32_16x16x32_bf16(pone, pm, zf, 0, 0, 0);
  int rowv[4], colv[4];
#pragma unroll
  for (int r = 0; r < 4; ++r) {
    rowv[r] = (int)(dr[r] * (1.0f / 32.0f) + 0.5f);
    colv[r] = (int)(dc[r] * (1.0f / 32.0f) + 0.5f);
  }
  __syncthreads();  // Acf/Ccf visible before first staging use

  // B staging: load 2x16B of Xp, apply BN+ReLU, write into Bsd (linear dest).
  auto stageB = [&](int kk, unsigned short* Bsd) {
    int cb = kk + qs * 8;
    float4 a0 = *(const float4*)&Acf[cb];
    float4 a1 = *(const float4*)&Acf[cb + 4];
    float4 c0 = *(const float4*)&Ccf[cb];
    float4 c1 = *(const float4*)&Ccf[cb + 4];
#pragma unroll
    for (int h = 0; h < 2; ++h) {
      uint4 raw = *(const uint4*)(Xp + (size_t)(j0 + h * 64 + brow) * kCO + cb);
      const unsigned short* rs = (const unsigned short*)&raw;
      unsigned short o8[8];
      o8[0] = f2bf(fmaxf(fmaf(a0.x, bf2f(rs[0]), c0.x), 0.f));
      o8[1] = f2bf(fmaxf(fmaf(a0.y, bf2f(rs[1]), c0.y), 0.f));
      o8[2] = f2bf(fmaxf(fmaf(a0.z, bf2f(rs[2]), c0.z), 0.f));
      o8[3] = f2bf(fmaxf(fmaf(a0.w, bf2f(rs[3]), c0.w), 0.f));
      o8[4] = f2bf(fmaxf(fmaf(a1.x, bf2f(rs[4]), c1.x), 0.f));
      o8[5] = f2bf(fmaxf(fmaf(a1.y, bf2f(rs[5]), c1.y), 0.f));
      o8[6] = f2bf(fmaxf(fmaf(a1.z, bf2f(rs[6]), c1.z), 0.f));
      o8[7] = f2bf(fmaxf(fmaf(a1.w, bf2f(rs[7]), c1.w), 0.f));
      *(uint4*)&Bsd[(size_t)(tid + h * 256) * 8] = *(uint4*)o8;
    }
  };

  // prologue: stage K-step 0 into buffer 0
  cp16_async(Wbf + (size_t)(m0 + brow) * KDIM + qs * 8, &smem[(size_t)tid * 8]);
  cp16_async(Wbf + (size_t)(m0 + 64 + brow) * KDIM + qs * 8, &smem[(size_t)(tid + 256) * 8]);
  stageB(0, smem + 4096);
  __syncthreads();

  f32x4 acc[4][4] = {};
  int cur = 0;
  for (int k0 = 0; k0 < KDIM; k0 += 32) {
    unsigned short* As = smem + cur * 8192;
    unsigned short* Bs = As + 4096;
    int kn = k0 + 32;
    if (kn < KDIM) {
      unsigned short* An = smem + (cur ^ 1) * 8192;
      cp16_async(Wbf + (size_t)(m0 + brow) * KDIM + kn + qs * 8, &An[(size_t)tid * 8]);
      cp16_async(Wbf + (size_t)(m0 + 64 + brow) * KDIM + kn + qs * 8, &An[(size_t)(tid + 256) * 8]);
      stageB(kn, An + 4096);
    }
    bf16x8 af[4], bfr[4];
#pragma unroll
    for (int mt = 0; mt < 4; ++mt)
      af[mt] = *(const bf16x8*)(&As[(wm * 64 + mt * 16 + l16) * 32 + qsw * 8]);
#pragma unroll
    for (int nt = 0; nt < 4; ++nt)
      bfr[nt] = *(const bf16x8*)(&Bs[(wn * 64 + nt * 16 + l16) * 32 + qsw * 8]);
#pragma unroll
    for (int mt = 0; mt < 4; ++mt)
#pragma unroll
      for (int nt = 0; nt < 4; ++nt)
        acc[mt][nt] = __builtin_amdgcn_mfma_f32_16x16x32_bf16(af[mt], bfr[nt], acc[mt][nt], 0, 0, 0);
    __syncthreads();
    cur ^= 1;
  }

#pragma unroll
  for (int mt = 0; mt < 4; ++mt) {
#pragma unroll
    for (int r = 0; r < 4; ++r) {
      int ol = wm * 64 + mt * 16 + rowv[r];
      int o = m0 + ol;
      float bv = bias[o];
      float s = 0.f, qq = 0.f;
#pragma unroll
      for (int nt = 0; nt < 4; ++nt) {
        int j = j0 + wn * 64 + nt * 16 + colv[r];
        float v = acc[mt][nt][r] + bv;
        s += v; qq += v * v;
        int bb = j >> 14, nn = j & (kN - 1);
        out[((size_t)(bb * kCO + o)) * kN + nn] = v;
      }
#pragma unroll
      for (int d2 = 1; d2 < 16; d2 <<= 1) {
        s += __shfl_xor(s, d2, 64);
        qq += __shfl_xor(qq, d2, 64);
      }
      if (l16 == 0) {
        psum[wn][ol] = s;
        pq[wn][ol] = qq;
      }
    }
  }
  __syncthreads();
  if (tid < 128) {
    float ss = psum[0][tid] + psum[1][tid];
    float qq = pq[0][tid] + pq[1][tid];
    partS[(size_t)(m0 + tid) * 512 + blockIdx.x] = ss;
    partQ[(size_t)(m0 + tid) * 512 + blockIdx.x] = qq;
  }
}

// Final BN+ReLU with inlined stats reduction: each block spans 1024 elements
// of a single channel o; reduces part[o][0..512) (contiguous, L2-hot) and
// applies the affine in one pass.
__global__ __launch_bounds__(256) void finalf_kernel(
    float* __restrict__ Y, const float* __restrict__ pS,
    const float* __restrict__ pQ, const float* __restrict__ gamma,
    const float* __restrict__ beta) {
  __shared__ float sw[4], qw[4], coef[2];
  size_t base = (size_t)blockIdx.x * 1024;
  int o = (int)((base >> 14) & (kCO - 1));
  int tid = threadIdx.x;
  float s = pS[(size_t)o * 512 + tid] + pS[(size_t)o * 512 + 256 + tid];
  float q = pQ[(size_t)o * 512 + tid] + pQ[(size_t)o * 512 + 256 + tid];
#pragma unroll
  for (int d = 1; d < 64; d <<= 1) {
    s += __shfl_xor(s, d, 64);
    q += __shfl_xor(q, d, 64);
  }
  if ((tid & 63) == 0) { sw[tid >> 6] = s; qw[tid >> 6] = q; }
  __syncthreads();
  if (tid == 0) {
    float st = (sw[0] + sw[1]) + (sw[2] + sw[3]);
    float qt = (qw[0] + qw[1]) + (qw[2] + qw[3]);
    float m = st * (1.0f / 65536.f);
    float var = qt * (1.0f / 65536.f) - m * m;
    float rsq = 1.0f / sqrtf(var + 1e-5f);
    float a = gamma[o] * rsq;
    coef[0] = a;
    coef[1] = beta[o] - m * a;
  }
  __syncthreads();
  float a = coef[0], c = coef[1];
  float4 u = *(float4*)(Y + base + tid * 4);
  float* t = (float*)&u;
#pragma unroll
  for (int k = 0; k < 4; ++k) t[k] = fmaxf(fmaf(a, t[k], c), 0.0f);
  *(float4*)(Y + base + tid * 4) = u;
}

}  // namespace

extern "C" void kernel_launch(void* const* d_in, const int* in_sizes, int n_in,
                              void* d_out, int out_size, void* d_ws, size_t ws_size,
                              hipStream_t stream) {
  const float* xyz1 = (const float*)d_in[0];
  const float* xyz2 = (const float*)d_in[1];
  const float* fea1 = (const float*)d_in[2];
  const float* fea2 = (const float*)d_in[3];
  const float* W0 = (const float*)d_in[4];
  const float* b0 = (const float*)d_in[5];
  const float* g0 = (const float*)d_in[6];
  const float* be0 = (const float*)d_in[7];
  const float* W1 = (const float*)d_in[8];
  const float* b1 = (const float*)d_in[9];
  const float* g1 = (const float*)d_in[10];
  const float* be1 = (const float*)d_in[11];
  float* out = (float*)d_out;

  char* ws = (char*)d_ws;
  float4* pts4 = (float4*)ws;
  float* ab0 = (float*)(ws + kOffAb0);
  unsigned short* X1pre = (unsigned short*)(ws + kOffX1p);
  float* partS = (float*)(ws + kOffPart);
  float* partQ = (float*)(ws + kOffPart + 524288);
  float* fea2t = (float*)(ws + kOffPart);          // overlays partials, dead after knn
  unsigned short* W0bf = (unsigned short*)(ws + kOffWbf);
  unsigned short* W1bf = (unsigned short*)(ws + kOffW1bf);
  unsigned short* XT = (unsigned short*)d_out;     // bf16 [65536][384], dead after gemm0

  if (ws_size < kOffW1bf + (size_t)kCO * kCO * 2) return;

  prep_kernel<<<2152, 256, 0, stream>>>(xyz2, pts4, fea2, fea2t, fea1, XT,
                                        W0, W1, W0bf, W1bf);
  knn_interp_kernel<<<kNCOL / 64, 512, 0, stream>>>(xyz1, pts4, fea2t, XT);
  gemm0t_kernel<<<dim3(kNCOL / 128, kCO / 128), 256, 0, stream>>>(W0bf, XT, b0, X1pre, partS, partQ);
  redstats_kernel<<<kCO, 64, 0, stream>>>(partS, partQ, g0, be0, ab0);
  gemm1f_kernel<<<dim3(kNCOL / 128, kCO / 128), 256, 0, stream>>>(W1bf, X1pre, b1, ab0, out, partS, partQ);
  finalf_kernel<<<kCO * kNCOL / (256 * 4), 256, 0, stream>>>(out, partS, partQ, g1, be1);
}